// Round 6
// baseline (41.319 us; speedup 1.0000x reference)
//
#include <hip/hip_runtime.h>

// SpatialCoherenceLoss — R6: R4 structure + nontemporal prep stores (R5 fixed:
// __builtin_nontemporal_* needs ext_vector_type, not HIP_vector_type).
// Hypothesis under test: the ~22us/block-generation floor in R2-R4 is cross-XCD
// dirty-line bounce on prep-written ws lines; nt stores push them out of the
// writing XCD's L2 so all XCDs fetch clean.
// loss = mean_{i,j} exp(-100*||s_i-s_j||^2) * (sq_i + sq_j - 2<p_i,p_j>)

#define NPTS 8192
#define DIM  64
#define TILE 128
#define NT   (NPTS / TILE)             // 64
#define NITEMS (NT * (NT + 1) / 2)     // 2080
#define IPB  2
#define NBLK (NITEMS / IPB)            // 1040

typedef __attribute__((ext_vector_type(8))) short bf16x8;
typedef __attribute__((ext_vector_type(4))) float f32x4;
typedef __attribute__((ext_vector_type(4))) float fv4;
typedef __attribute__((ext_vector_type(4))) ushort usv4;

#define AS3(p) ((__attribute__((address_space(3))) void*)(p))
#define AS1(p) ((const __attribute__((address_space(1))) void*)(p))

__device__ __forceinline__ ushort f2bf(float x) {
    unsigned u = __builtin_bit_cast(unsigned, x);
    unsigned r = (u + 0x7fffu + ((u >> 16) & 1u)) >> 16;
    return (ushort)r;
}
__device__ __forceinline__ float bf2f(ushort b) {
    unsigned u = ((unsigned)b) << 16;
    return __builtin_bit_cast(float, u);
}

constexpr float kCoordScale = 12.0112244f;  // sqrt(100*log2(e))

__global__ void scl_prep_kernel(const float* __restrict__ pred,
                                const float* __restrict__ spat,
                                ushort* __restrict__ pbf,
                                float4* __restrict__ params,
                                unsigned* __restrict__ ctr) {
    int i = blockIdx.x * blockDim.x + threadIdx.x;
    if (i == 0) ctr[0] = 0u;
    const fv4* pr = (const fv4*)(pred + (size_t)i * DIM);
    usv4* po = (usv4*)(pbf + (size_t)i * DIM);
    float sq = 0.f;
    #pragma unroll
    for (int k = 0; k < DIM / 4; ++k) {
        fv4 v = __builtin_nontemporal_load(&pr[k]);
        usv4 o;
        o.x = f2bf(v.x); o.y = f2bf(v.y); o.z = f2bf(v.z); o.w = f2bf(v.w);
        float a = bf2f(o.x), b = bf2f(o.y), c = bf2f(o.z), d = bf2f(o.w);
        sq += a * a + b * b + c * c + d * d;
        __builtin_nontemporal_store(o, &po[k]);   // nt: don't leave dirty in L2
    }
    fv4 pm;
    pm.x = sq;
    pm.y = spat[2 * i] * kCoordScale;
    pm.z = spat[2 * i + 1] * kCoordScale;
    pm.w = 0.f;
    __builtin_nontemporal_store(pm, (fv4*)&params[i]);  // nt
}

// LDS: B0[16K) B1[16K) P0[2K) P1[2K)  = 36 KB (+red) -> 4 blocks/CU.
__launch_bounds__(256)
__global__ void scl_mfma_kernel(const ushort* __restrict__ pbf,
                                const float4* __restrict__ params,
                                float* __restrict__ partial,
                                unsigned* __restrict__ ctr,
                                float* __restrict__ out) {
    __shared__ __align__(16) char smem[36864];
    __shared__ float red[4];
    __shared__ int lastflag;

    const int tid  = threadIdx.x;
    const int lane = tid & 63;
    const int wave = tid >> 6;
    const int fr = lane & 15;
    const int h  = lane >> 4;

    int t = blockIdx.x * IPB;
    int bi = 0, base = 0;
    while (base + (NT - bi) <= t) { base += NT - bi; ++bi; }
    int bj = bi + (t - base);

    bf16x8 afrag[2][2];
    float rsq[2][4], rsx[2][4], rsy[2][4];
    auto loadA = [&](int bi_) {
        int ti = bi_ * TILE;
        #pragma unroll
        for (int rb = 0; rb < 2; ++rb) {
            int row = ti + wave * 32 + rb * 16 + fr;
            #pragma unroll
            for (int ks = 0; ks < 2; ++ks)
                afrag[rb][ks] =
                    *(const bf16x8*)(pbf + (size_t)row * DIM + ks * 32 + h * 8);
            #pragma unroll
            for (int reg = 0; reg < 4; ++reg) {
                float4 rp = params[ti + wave * 32 + rb * 16 + h * 4 + reg];
                rsq[rb][reg] = rp.x; rsx[rb][reg] = rp.y; rsy[rb][reg] = rp.z;
            }
        }
    };

    auto stageB = [&](int bj_, int buf) {
        const char* gB = (const char*)(pbf + (size_t)bj_ * TILE * DIM);
        #pragma unroll
        for (int it = 0; it < 4; ++it) {
            unsigned L = (unsigned)tid * 16u + (unsigned)it * 4096u;
            unsigned row = L >> 7;
            unsigned src = (L & ~127u) | ((L & 127u) ^ ((row & 7u) << 4));
            unsigned dst = (unsigned)buf * 16384u + (unsigned)wave * 1024u +
                           (unsigned)it * 4096u;
            __builtin_amdgcn_global_load_lds(AS1(gB + src), AS3(smem + dst), 16, 0, 0);
        }
        if (wave < 2) {
            const char* gp = (const char*)(params + bj_ * TILE);
            unsigned so = (unsigned)wave * 1024u + (unsigned)lane * 16u;
            __builtin_amdgcn_global_load_lds(
                AS1(gp + so),
                AS3(smem + 32768u + (unsigned)buf * 2048u + (unsigned)wave * 1024u),
                16, 0, 0);
        }
    };

    loadA(bi);
    int abi = bi;
    stageB(bj, 0);

    float loss = 0.f;
    int cur = 0, cbi = bi, cbj = bj;
    #pragma unroll 1
    for (int k = 0; k < IPB; ++k) {
        int nbi = cbi, nbj = cbj + 1;
        if (nbj == NT) { nbi = cbi + 1; nbj = nbi; }

        asm volatile("s_waitcnt vmcnt(0)" ::: "memory");
        __syncthreads();

        if (cbi != abi) { loadA(cbi); abi = cbi; }
        if (k + 1 < IPB) stageB(nbj, cur ^ 1);

        const char* bB = smem + (unsigned)cur * 16384u;
        const float4* pBl = (const float4*)(smem + 32768u + (unsigned)cur * 2048u);

        float tl = 0.f;
        #pragma unroll
        for (int half = 0; half < 2; ++half) {
            f32x4 acc[2][4];
            #pragma unroll
            for (int rb = 0; rb < 2; ++rb)
                #pragma unroll
                for (int c4 = 0; c4 < 4; ++c4)
                    acc[rb][c4] = (f32x4){0.f, 0.f, 0.f, 0.f};

            #pragma unroll
            for (int c4 = 0; c4 < 4; ++c4) {
                unsigned rowB = (unsigned)((half * 4 + c4) * 16 + fr);
                unsigned sw = (rowB & 7u) << 4;
                const char* bb = bB + rowB * 128u;
                bf16x8 b0 = *(const bf16x8*)(bb + (((unsigned)(h * 16)) ^ sw));
                bf16x8 b1 = *(const bf16x8*)(bb + (((unsigned)(64 + h * 16)) ^ sw));
                #pragma unroll
                for (int rb = 0; rb < 2; ++rb) {
                    acc[rb][c4] = __builtin_amdgcn_mfma_f32_16x16x32_bf16(
                        afrag[rb][0], b0, acc[rb][c4], 0, 0, 0);
                    acc[rb][c4] = __builtin_amdgcn_mfma_f32_16x16x32_bf16(
                        afrag[rb][1], b1, acc[rb][c4], 0, 0, 0);
                }
            }

            #pragma unroll
            for (int c4 = 0; c4 < 4; ++c4) {
                float4 cp = pBl[(half * 4 + c4) * 16 + fr];
                #pragma unroll
                for (int rb = 0; rb < 2; ++rb)
                    #pragma unroll
                    for (int reg = 0; reg < 4; ++reg) {
                        float dot = acc[rb][c4][reg];
                        float dx = rsx[rb][reg] - cp.y;
                        float dy = rsy[rb][reg] - cp.z;
                        float nd2 = fmaf(-dx, dx, (-dy) * dy);
                        float w = __builtin_amdgcn_exp2f(nd2);
                        float pd = fmaf(-2.f, dot, rsq[rb][reg] + cp.x);
                        tl = fmaf(w, pd, tl);
                    }
            }
        }
        loss += (cbi != cbj) ? 2.f * tl : tl;
        cur ^= 1; cbi = nbi; cbj = nbj;
    }

    #pragma unroll
    for (int off = 32; off > 0; off >>= 1)
        loss += __shfl_down(loss, off, 64);
    if (lane == 0) red[wave] = loss;
    __syncthreads();
    if (tid == 0) {
        partial[blockIdx.x] = (red[0] + red[1]) + (red[2] + red[3]);
        __threadfence();
        unsigned old = atomicAdd(ctr, 1u);
        lastflag = (old == (unsigned)(NBLK - 1)) ? 1 : 0;
        if (lastflag) __threadfence();
    }
    __syncthreads();
    if (lastflag) {
        float s = 0.f;
        for (int idx = tid; idx < NBLK; idx += 256) s += partial[idx];
        #pragma unroll
        for (int off = 32; off > 0; off >>= 1)
            s += __shfl_down(s, off, 64);
        if (lane == 0) red[wave] = s;
        __syncthreads();
        if (tid == 0)
            out[0] = ((red[0] + red[1]) + (red[2] + red[3])) *
                     (1.0f / (8192.0f * 8192.0f));
    }
}

extern "C" void kernel_launch(void* const* d_in, const int* in_sizes, int n_in,
                              void* d_out, int out_size, void* d_ws, size_t ws_size,
                              hipStream_t stream) {
    const float* pred = (const float*)d_in[0];
    const float* spat = (const float*)d_in[1];
    float* out = (float*)d_out;

    ushort*   pbf     = (ushort*)d_ws;                                    // 1 MB
    float4*   params  = (float4*)((char*)d_ws + (size_t)NPTS * DIM * 2);  // 128 KB
    float*    partial = (float*)((char*)params + NPTS * sizeof(float4));  // 4.2 KB
    unsigned* ctr     = (unsigned*)(partial + ((NBLK + 3) & ~3));

    scl_prep_kernel<<<NPTS / 256, 256, 0, stream>>>(pred, spat, pbf, params, ctr);
    scl_mfma_kernel<<<NBLK, 256, 0, stream>>>(pbf, params, partial, ctr, out);
}

// Round 8
// 36.642 us; speedup vs baseline: 1.1276x; 1.1276x over previous
//
#include <hip/hip_runtime.h>

// SpatialCoherenceLoss — R8: R7 with the params-staging bug fixed (global
// source of global_load_lds is PER-LANE; R7 passed a uniform address, so all
// lanes fetched the same 16B — rule m104). Structure unchanged: 2x2
// super-tiles (4 items / 4 tile-stages, 528 blocks), all frags from LDS,
// counted vmcnt(8) so item(0,0) computes under R1/C1 staging.
// loss = mean_{i,j} exp(-100*||s_i-s_j||^2) * (sq_i + sq_j - 2<p_i,p_j>)

#define NPTS 8192
#define DIM  64
#define TILE 128
#define NT   (NPTS / TILE)              // 64 tiles
#define NSG  (NT / 2)                   // 32 super rows
#define NSUP (NSG * (NSG + 1) / 2)      // 528 blocks

typedef __attribute__((ext_vector_type(8))) short bf16x8;
typedef __attribute__((ext_vector_type(4))) float f32x4;
typedef __attribute__((ext_vector_type(4))) float fv4;
typedef __attribute__((ext_vector_type(4))) ushort usv4;

#define AS3(p) ((__attribute__((address_space(3))) void*)(p))
#define AS1(p) ((const __attribute__((address_space(1))) void*)(p))

__device__ __forceinline__ ushort f2bf(float x) {
    unsigned u = __builtin_bit_cast(unsigned, x);
    unsigned r = (u + 0x7fffu + ((u >> 16) & 1u)) >> 16;
    return (ushort)r;
}
__device__ __forceinline__ float bf2f(ushort b) {
    unsigned u = ((unsigned)b) << 16;
    return __builtin_bit_cast(float, u);
}

constexpr float kCoordScale = 12.0112244f;  // sqrt(100*log2(e))

__global__ void scl_prep_kernel(const float* __restrict__ pred,
                                const float* __restrict__ spat,
                                ushort* __restrict__ pbf,
                                float4* __restrict__ params,
                                unsigned* __restrict__ ctr) {
    int i = blockIdx.x * blockDim.x + threadIdx.x;
    if (i == 0) ctr[0] = 0u;
    const fv4* pr = (const fv4*)(pred + (size_t)i * DIM);
    usv4* po = (usv4*)(pbf + (size_t)i * DIM);
    float sq = 0.f;
    #pragma unroll
    for (int k = 0; k < DIM / 4; ++k) {
        fv4 v = __builtin_nontemporal_load(&pr[k]);
        usv4 o;
        o.x = f2bf(v.x); o.y = f2bf(v.y); o.z = f2bf(v.z); o.w = f2bf(v.w);
        float a = bf2f(o.x), b = bf2f(o.y), c = bf2f(o.z), d = bf2f(o.w);
        sq += a * a + b * b + c * c + d * d;
        __builtin_nontemporal_store(o, &po[k]);
    }
    fv4 pm;
    pm.x = sq;
    pm.y = spat[2 * i] * kCoordScale;
    pm.z = spat[2 * i + 1] * kCoordScale;
    pm.w = 0.f;
    __builtin_nontemporal_store(pm, (fv4*)&params[i]);
}

// LDS: 4 tile slots x 16KB = 64KB @0, 4 param slots x 2KB @65536. 73.75KB
// -> 2 blocks/CU. Slots: 0=R0(2si) 1=R1(2si+1) 2=C0(2sj) 3=C1(2sj+1).
__launch_bounds__(256, 2)
__global__ void scl_mfma_kernel(const ushort* __restrict__ pbf,
                                const float4* __restrict__ params,
                                float* __restrict__ partial,
                                unsigned* __restrict__ ctr,
                                float* __restrict__ out) {
    __shared__ __align__(16) char smem[73728];
    __shared__ float red[4];
    __shared__ int lastflag;

    const int tid  = threadIdx.x;
    const int lane = tid & 63;
    const int wave = tid >> 6;
    const int fr = lane & 15;
    const int h  = lane >> 4;

    // triangular decode over 32x32 super grid
    int t = blockIdx.x;
    int si = 0, base = 0;
    while (base + (NSG - si) <= t) { base += NSG - si; ++si; }
    const int sj = si + (t - base);
    const bool diag = (si == sj);

    const int tiles[4] = {2 * si, 2 * si + 1, 2 * sj, 2 * sj + 1};

    auto stageTile = [&](int slot) {
        const char* g = (const char*)(pbf + (size_t)tiles[slot] * TILE * DIM);
        #pragma unroll
        for (int it = 0; it < 4; ++it) {
            unsigned L = (unsigned)tid * 16u + (unsigned)it * 4096u;
            unsigned row = L >> 7;
            unsigned src = (L & ~127u) | ((L & 127u) ^ ((row & 7u) << 4));
            unsigned dst = (unsigned)slot * 16384u + (unsigned)wave * 1024u +
                           (unsigned)it * 4096u;
            __builtin_amdgcn_global_load_lds(AS1(g + src), AS3(smem + dst), 16, 0, 0);
        }
    };

    // issue order: R0, C0 (needed first), own-slot params, then R1, C1
    stageTile(0);
    stageTile(2);
    {   // wave w stages params for slot w (2 x 1KB); source must be PER-LANE
        const char* gp = (const char*)(params + tiles[wave] * TILE);
        #pragma unroll
        for (int it = 0; it < 2; ++it) {
            unsigned so  = (unsigned)it * 1024u + (unsigned)lane * 16u;  // R7 bug: lane*16 was missing
            unsigned dst = 65536u + (unsigned)wave * 2048u + (unsigned)it * 1024u;
            __builtin_amdgcn_global_load_lds(AS1(gp + so), AS3(smem + dst), 16, 0, 0);
        }
    }
    stageTile(1);
    stageTile(3);

    auto computeItem = [&](int sa, int sb) -> float {
        const char* aB = smem + (unsigned)sa * 16384u;
        const char* bB = smem + (unsigned)sb * 16384u;
        const float4* pA = (const float4*)(smem + 65536u + (unsigned)sa * 2048u);
        const float4* pB = (const float4*)(smem + 65536u + (unsigned)sb * 2048u);

        bf16x8 afrag[2][2];
        #pragma unroll
        for (int rb = 0; rb < 2; ++rb)
            #pragma unroll
            for (int ks = 0; ks < 2; ++ks) {
                unsigned row = (unsigned)(wave * 32 + rb * 16 + fr);
                unsigned off = (unsigned)(ks * 64 + h * 16);
                afrag[rb][ks] =
                    *(const bf16x8*)(aB + row * 128u + (off ^ ((row & 7u) << 4)));
            }

        f32x4 acc[2][8];
        #pragma unroll
        for (int rb = 0; rb < 2; ++rb)
            #pragma unroll
            for (int cb = 0; cb < 8; ++cb)
                acc[rb][cb] = (f32x4){0.f, 0.f, 0.f, 0.f};

        #pragma unroll
        for (int cb = 0; cb < 8; ++cb) {
            unsigned rowB = (unsigned)(cb * 16 + fr);
            unsigned sw = (rowB & 7u) << 4;
            const char* bb = bB + rowB * 128u;
            bf16x8 b0 = *(const bf16x8*)(bb + (((unsigned)(h * 16)) ^ sw));
            bf16x8 b1 = *(const bf16x8*)(bb + (((unsigned)(64 + h * 16)) ^ sw));
            #pragma unroll
            for (int rb = 0; rb < 2; ++rb) {
                acc[rb][cb] = __builtin_amdgcn_mfma_f32_16x16x32_bf16(
                    afrag[rb][0], b0, acc[rb][cb], 0, 0, 0);
                acc[rb][cb] = __builtin_amdgcn_mfma_f32_16x16x32_bf16(
                    afrag[rb][1], b1, acc[rb][cb], 0, 0, 0);
            }
        }

        float rsq[2][4], rsx[2][4], rsy[2][4];
        #pragma unroll
        for (int rb = 0; rb < 2; ++rb)
            #pragma unroll
            for (int reg = 0; reg < 4; ++reg) {
                float4 rp = pA[wave * 32 + rb * 16 + h * 4 + reg];
                rsq[rb][reg] = rp.x; rsx[rb][reg] = rp.y; rsy[rb][reg] = rp.z;
            }

        float tl = 0.f;
        #pragma unroll
        for (int cb = 0; cb < 8; ++cb) {
            float4 cp = pB[cb * 16 + fr];
            #pragma unroll
            for (int rb = 0; rb < 2; ++rb)
                #pragma unroll
                for (int reg = 0; reg < 4; ++reg) {
                    float dot = acc[rb][cb][reg];
                    float dx = rsx[rb][reg] - cp.y;
                    float dy = rsy[rb][reg] - cp.z;
                    float nd2 = fmaf(-dx, dx, (-dy) * dy);
                    float w = __builtin_amdgcn_exp2f(nd2);
                    float pd = fmaf(-2.f, dot, rsq[rb][reg] + cp.x);
                    tl = fmaf(w, pd, tl);
                }
        }
        return tl;
    };

    float loss = 0.f;

    // slots 0,2 + all params ready (per-wave oldest 10 of 18 DMAs done)
    asm volatile("s_waitcnt vmcnt(8)" ::: "memory");
    __syncthreads();
    {
        float tl = computeItem(0, 2);              // (2si, 2sj)
        loss += diag ? tl : 2.f * tl;
    }
    // all slots ready
    asm volatile("s_waitcnt vmcnt(0)" ::: "memory");
    __syncthreads();
    loss += 2.f * computeItem(0, 3);               // (2si, 2sj+1): never diag
    if (!diag)
        loss += 2.f * computeItem(1, 2);           // (2si+1, 2sj)
    {
        float tl = computeItem(1, 3);              // (2si+1, 2sj+1)
        loss += diag ? tl : 2.f * tl;
    }

    #pragma unroll
    for (int off = 32; off > 0; off >>= 1)
        loss += __shfl_down(loss, off, 64);
    if (lane == 0) red[wave] = loss;
    __syncthreads();
    if (tid == 0) {
        partial[blockIdx.x] = (red[0] + red[1]) + (red[2] + red[3]);
        __threadfence();
        unsigned old = atomicAdd(ctr, 1u);
        lastflag = (old == (unsigned)(NSUP - 1)) ? 1 : 0;
        if (lastflag) __threadfence();
    }
    __syncthreads();
    if (lastflag) {
        float s = 0.f;
        for (int idx = tid; idx < NSUP; idx += 256) s += partial[idx];
        #pragma unroll
        for (int off = 32; off > 0; off >>= 1)
            s += __shfl_down(s, off, 64);
        if (lane == 0) red[wave] = s;
        __syncthreads();
        if (tid == 0)
            out[0] = ((red[0] + red[1]) + (red[2] + red[3])) *
                     (1.0f / (8192.0f * 8192.0f));
    }
}

extern "C" void kernel_launch(void* const* d_in, const int* in_sizes, int n_in,
                              void* d_out, int out_size, void* d_ws, size_t ws_size,
                              hipStream_t stream) {
    const float* pred = (const float*)d_in[0];
    const float* spat = (const float*)d_in[1];
    float* out = (float*)d_out;

    ushort*   pbf     = (ushort*)d_ws;                                    // 1 MB
    float4*   params  = (float4*)((char*)d_ws + (size_t)NPTS * DIM * 2);  // 128 KB
    float*    partial = (float*)((char*)params + NPTS * sizeof(float4));  // 2.1 KB
    unsigned* ctr     = (unsigned*)(partial + ((NSUP + 3) & ~3));

    scl_prep_kernel<<<NPTS / 256, 256, 0, stream>>>(pred, spat, pbf, params, ctr);
    scl_mfma_kernel<<<NSUP, 256, 0, stream>>>(pbf, params, partial, ctr, out);
}